// Round 12
// baseline (1155.837 us; speedup 1.0000x reference)
//
#include <hip/hip_runtime.h>
#include <hip/hip_bf16.h>

#define N_ 100000
#define E_ 3200000
#define DIM 300
#define HID 16
#define NGRAPH 5
#define NB 196         // buckets/graph, 512 nodes each (196*512 >= 100000)
#define BSH 9
#define BNODES 512
#define CAP 20480      // mean 16384 edges/bucket, sigma~128 -> +32 sigma
#define SCAP 24576     // CAP + 512*8 padding headroom (24064 worst case)
#define NPAD (N_ + 8)  // hd/t stride: slot N_ is the zero "dummy" node

__device__ __forceinline__ void fatomic(float* p, float v) { unsafeAtomicAdd(p, v); }

// ---- phase 1: LDS-staged radix bucketing (R9-proven: register-staged, CHUNK 4096)
__global__ __launch_bounds__(256) void bucket_kernel(const int* __restrict__ ei,
                                                     unsigned* __restrict__ bcur,
                                                     unsigned* __restrict__ bedge) {
    int g = blockIdx.y;
    const int4* src4 = (const int4*)(ei + (size_t)g * 2 * E_);
    const int4* dst4 = (const int4*)(ei + (size_t)g * 2 * E_ + E_);
    unsigned* bc = bcur + (size_t)g * NB;
    unsigned* be = bedge + (size_t)g * NB * CAP;
    __shared__ unsigned hist[NB], curs[NB];
    int tid = threadIdx.x;
    const int CHUNK = 4096;
    const int nchunk = (E_ + CHUNK - 1) / CHUNK;
    for (int c = blockIdx.x; c < nchunk; c += gridDim.x) {
        int cb = c * CHUNK;
        for (int i = tid; i < NB; i += 256) hist[i] = 0u;
        __syncthreads();
        int4 sv[4], dv[4]; bool val[4];
#pragma unroll
        for (int k = 0; k < 4; ++k) {
            int e0 = cb + k * 1024 + tid * 4;
            val[k] = (e0 < E_);
            if (val[k]) { sv[k] = src4[e0 >> 2]; dv[k] = dst4[e0 >> 2]; }
        }
#pragma unroll
        for (int k = 0; k < 4; ++k) if (val[k]) {
            atomicAdd(&hist[((unsigned)dv[k].x) >> BSH], 1u);
            atomicAdd(&hist[((unsigned)dv[k].y) >> BSH], 1u);
            atomicAdd(&hist[((unsigned)dv[k].z) >> BSH], 1u);
            atomicAdd(&hist[((unsigned)dv[k].w) >> BSH], 1u);
        }
        __syncthreads();
        for (int i = tid; i < NB; i += 256) curs[i] = atomicAdd(&bc[i], hist[i]);
        __syncthreads();
#define EMIT(S, D) { unsigned bb = ((unsigned)(D)) >> BSH; \
        unsigned pos = atomicAdd(&curs[bb], 1u); \
        if (pos < CAP) be[(size_t)bb * CAP + pos] = (((unsigned)(S)) << BSH) | (((unsigned)(D)) & (BNODES - 1)); }
#pragma unroll
        for (int k = 0; k < 4; ++k) if (val[k]) {
            EMIT(sv[k].x, dv[k].x)
            EMIT(sv[k].y, dv[k].y)
            EMIT(sv[k].z, dv[k].z)
            EMIT(sv[k].w, dv[k].w)
        }
#undef EMIT
        __syncthreads();
    }
}

// ---- phase 1.5: per-bucket counting sort + pad-fill (dummy node N_) -----------
__global__ __launch_bounds__(256) void sortb_kernel(const unsigned* __restrict__ bcur,
                                                    const unsigned* __restrict__ bedge,
                                                    unsigned* __restrict__ ssrc,
                                                    unsigned* __restrict__ offA,
                                                    unsigned* __restrict__ degA,
                                                    float* __restrict__ dis) {
    int g = blockIdx.y, b = blockIdx.x;
    __shared__ unsigned hist[BNODES], offL[BNODES], curL[BNODES], part[256];
    int tid = threadIdx.x;
    hist[tid] = 0u; hist[tid + 256] = 0u;
    __syncthreads();
    unsigned n = bcur[(size_t)g * NB + b]; if (n > CAP) n = CAP;
    const unsigned* beb = bedge + ((size_t)g * NB + b) * CAP;
    for (unsigned i = tid; i < n; i += 256) atomicAdd(&hist[beb[i] & (BNODES - 1)], 1u);
    __syncthreads();
    unsigned d0 = hist[2 * tid], d1 = hist[2 * tid + 1];
    unsigned p0 = (d0 + 7u) & ~7u, p1 = (d1 + 7u) & ~7u;
    part[tid] = p0 + p1;
    __syncthreads();
    for (int o = 1; o < 256; o <<= 1) {
        unsigned v = (tid >= o) ? part[tid - o] : 0u;
        __syncthreads();
        part[tid] += v;
        __syncthreads();
    }
    unsigned base = part[tid] - p0 - p1;   // exclusive, multiple of 8
    offL[2 * tid] = base;         curL[2 * tid] = base;
    offL[2 * tid + 1] = base + p0; curL[2 * tid + 1] = base + p0;
    int node0 = b << BSH;
    unsigned sbase = (unsigned)(((size_t)g * NB + b) * SCAP);
    float* disg = dis + (size_t)g * N_;
    unsigned* offg = offA + (size_t)g * (NB << BSH);
    unsigned* degg = degA + (size_t)g * (NB << BSH);
    {
        int i = 2 * tid, node = node0 + i;
        offg[node] = sbase + offL[i]; degg[node] = d0;
        if (node < N_) disg[node] = rsqrtf((float)d0 + 1.0f);
        for (unsigned k = d0; k < p0; ++k) ssrc[(size_t)sbase + offL[i] + k] = (unsigned)N_;
        i = 2 * tid + 1; node = node0 + i;
        offg[node] = sbase + offL[i]; degg[node] = d1;
        if (node < N_) disg[node] = rsqrtf((float)d1 + 1.0f);
        for (unsigned k = d1; k < p1; ++k) ssrc[(size_t)sbase + offL[i] + k] = (unsigned)N_;
    }
    __syncthreads();
    for (unsigned i = tid; i < n; i += 256) {
        unsigned pk = beb[i];
        unsigned pos = atomicAdd(&curL[pk & (BNODES - 1)], 1u);
        ssrc[(size_t)sbase + pos] = pk >> BSH;
    }
}

// ---- hd = (x @ W1) * dis: coalesced LDS-staged X tiles, 256 nodes/block -------
// X loads now coalesced (flat tile index); per-thread row reads from padded LDS.
#define CCH 20   // K-chunk width (300 = 15 * 20)
__global__ __launch_bounds__(256) void gemm_kernel(const float* __restrict__ x,
                                                   const float* __restrict__ W1,
                                                   const float* __restrict__ dis,
                                                   float* __restrict__ hd, int ngr) {
    __shared__ float wsh[DIM * HID];      // 19.2 KB
    __shared__ float xt[256 * (CCH + 1)]; // 21.5 KB, stride 21 (odd) -> conflict-free
    int tid = threadIdx.x;
    for (int i = tid; i < DIM * HID; i += 256) wsh[i] = W1[i];
    if (blockIdx.x == 0 && tid < ngr) {   // zero per-graph dummy line
        float4* pz = (float4*)(hd + ((size_t)tid * NPAD + N_) * HID);
        float4 z = {0.f, 0.f, 0.f, 0.f};
        pz[0] = z; pz[1] = z; pz[2] = z; pz[3] = z;
    }
    int ntot = ngr * N_;
    int node0 = blockIdx.x * 256;
    int node = node0 + tid;
    float4 a0 = {0,0,0,0}, a1 = {0,0,0,0}, a2 = {0,0,0,0}, a3 = {0,0,0,0};
#pragma unroll 1
    for (int c = 0; c < DIM / CCH; ++c) {
        __syncthreads();
        // coalesced tile load: 256 rows x CCH cols, flat index
#pragma unroll
        for (int it = 0; it < CCH; ++it) {
            int i = tid + it * 256;
            int row = i / CCH, col = i - row * CCH;
            int nd = node0 + row;
            xt[row * (CCH + 1) + col] = (nd < ntot) ? x[(size_t)nd * DIM + c * CCH + col] : 0.f;
        }
        __syncthreads();
        const float* xr = xt + tid * (CCH + 1);
#pragma unroll
        for (int k = 0; k < CCH; ++k) {
            float xs = xr[k];
            const float4* wr = (const float4*)(wsh + (c * CCH + k) * HID);
            float4 q0 = wr[0], q1 = wr[1], q2 = wr[2], q3 = wr[3];
            a0.x += xs * q0.x; a0.y += xs * q0.y; a0.z += xs * q0.z; a0.w += xs * q0.w;
            a1.x += xs * q1.x; a1.y += xs * q1.y; a1.z += xs * q1.z; a1.w += xs * q1.w;
            a2.x += xs * q2.x; a2.y += xs * q2.y; a2.z += xs * q2.z; a2.w += xs * q2.w;
            a3.x += xs * q3.x; a3.y += xs * q3.y; a3.z += xs * q3.z; a3.w += xs * q3.w;
        }
    }
    if (node < ntot) {
        float dn = dis[node];
        a0.x *= dn; a0.y *= dn; a0.z *= dn; a0.w *= dn;
        a1.x *= dn; a1.y *= dn; a1.z *= dn; a1.w *= dn;
        a2.x *= dn; a2.y *= dn; a2.z *= dn; a2.w *= dn;
        a3.x *= dn; a3.y *= dn; a3.z *= dn; a3.w *= dn;
        int gi = node / N_, local = node - gi * N_;
        float4* hr = (float4*)(hd + ((size_t)gi * NPAD + local) * HID);
        hr[0] = a0; hr[1] = a1; hr[2] = a2; hr[3] = a3;
    }
}

// ---- phase 2: per-node register aggregation, padded lists, 16-deep pipeline ---
__global__ __launch_bounds__(512) void bagg_kernel(const unsigned* __restrict__ ssrc,
                                                   const unsigned* __restrict__ offA,
                                                   const unsigned* __restrict__ degA,
                                                   const float* __restrict__ hd,
                                                   const float* __restrict__ dis,
                                                   const float* __restrict__ b1,
                                                   const float* __restrict__ W2,
                                                   float* __restrict__ t_) {
    int g = blockIdx.y, b = blockIdx.x;
    const float* hdg = hd + (size_t)g * NPAD * HID;
    const float* disg = dis + (size_t)g * N_;
    const unsigned* offg = offA + (size_t)g * (NB << BSH);
    const unsigned* degg = degA + (size_t)g * (NB << BSH);
    float* tg = t_ + (size_t)g * NPAD;
    int tid = threadIdx.x, j = tid & 15, sub = tid >> 4;   // 32 node-groups
    if (b == 0 && tid == 0) tg[N_] = 0.f;                  // dummy for score2
    float b1j = b1[j], w2j = W2[j];
    int node0 = b << BSH;
#pragma unroll 1
    for (int m = 0; m < 16; ++m) {
        int node = node0 + sub + (m << 5);
        if (node >= N_) continue;
        unsigned k0 = offg[node], dg = degg[node];
        unsigned dgp = (dg + 7u) & ~7u;                    // padded: multiple of 8
        float acc = hdg[(size_t)node * HID + j];           // self-loop term
        unsigned k = 0;
        for (; k + 16 <= dgp; k += 16) {                   // 16-deep gather pipeline
            const int4* ip = (const int4*)(ssrc + k0 + k);
            int4 i0 = ip[0], i1 = ip[1], i2 = ip[2], i3 = ip[3];
            float v0 = hdg[(size_t)(unsigned)i0.x * HID + j];
            float v1 = hdg[(size_t)(unsigned)i0.y * HID + j];
            float v2 = hdg[(size_t)(unsigned)i0.z * HID + j];
            float v3 = hdg[(size_t)(unsigned)i0.w * HID + j];
            float v4 = hdg[(size_t)(unsigned)i1.x * HID + j];
            float v5 = hdg[(size_t)(unsigned)i1.y * HID + j];
            float v6 = hdg[(size_t)(unsigned)i1.z * HID + j];
            float v7 = hdg[(size_t)(unsigned)i1.w * HID + j];
            float v8 = hdg[(size_t)(unsigned)i2.x * HID + j];
            float v9 = hdg[(size_t)(unsigned)i2.y * HID + j];
            float va = hdg[(size_t)(unsigned)i2.z * HID + j];
            float vb = hdg[(size_t)(unsigned)i2.w * HID + j];
            float vc = hdg[(size_t)(unsigned)i3.x * HID + j];
            float vd = hdg[(size_t)(unsigned)i3.y * HID + j];
            float ve = hdg[(size_t)(unsigned)i3.z * HID + j];
            float vf = hdg[(size_t)(unsigned)i3.w * HID + j];
            acc += (((v0 + v1) + (v2 + v3)) + ((v4 + v5) + (v6 + v7)))
                 + (((v8 + v9) + (va + vb)) + ((vc + vd) + (ve + vf)));
        }
        for (; k < dgp; k += 8) {
            const int4* ip = (const int4*)(ssrc + k0 + k);
            int4 i0 = ip[0], i1 = ip[1];
            float v0 = hdg[(size_t)(unsigned)i0.x * HID + j];
            float v1 = hdg[(size_t)(unsigned)i0.y * HID + j];
            float v2 = hdg[(size_t)(unsigned)i0.z * HID + j];
            float v3 = hdg[(size_t)(unsigned)i0.w * HID + j];
            float v4 = hdg[(size_t)(unsigned)i1.x * HID + j];
            float v5 = hdg[(size_t)(unsigned)i1.y * HID + j];
            float v6 = hdg[(size_t)(unsigned)i1.z * HID + j];
            float v7 = hdg[(size_t)(unsigned)i1.w * HID + j];
            acc += ((v0 + v1) + (v2 + v3)) + ((v4 + v5) + (v6 + v7));
        }
        float dn = disg[node];
        float val = fmaxf(acc * dn + b1j, 0.f) * w2j;
        val += __shfl_xor(val, 1);
        val += __shfl_xor(val, 2);
        val += __shfl_xor(val, 4);
        val += __shfl_xor(val, 8);
        if (j == 0) tg[node] = val * dn;
    }
}

// ---- layer-2 via sorted padded lists ------------------------------------------
__global__ __launch_bounds__(512) void score2_kernel(const unsigned* __restrict__ ssrc,
                                                     const unsigned* __restrict__ offA,
                                                     const unsigned* __restrict__ degA,
                                                     const float* __restrict__ t_,
                                                     const float* __restrict__ dis,
                                                     float* __restrict__ S) {
    int g = blockIdx.y, b = blockIdx.x;
    const float* tg = t_ + (size_t)g * NPAD;
    const float* disg = dis + (size_t)g * N_;
    const unsigned* offg = offA + (size_t)g * (NB << BSH);
    const unsigned* degg = degA + (size_t)g * (NB << BSH);
    int tid = threadIdx.x, j = tid & 3, grp = tid >> 2;   // 128 node-groups
    int node0 = b << BSH;
    float c = 0.f;
#pragma unroll 1
    for (int m = 0; m < 4; ++m) {
        int node = node0 + grp + (m << 7);
        if (node >= N_) continue;
        unsigned k0 = offg[node], dg = degg[node];
        unsigned dgp = (dg + 7u) & ~7u;                   // t[N_] == 0: pads add 0
        float acc = 0.f;
        for (unsigned k = j; k < dgp; k += 4) acc += tg[ssrc[k0 + k]];
        acc += __shfl_xor(acc, 1);
        acc += __shfl_xor(acc, 2);
        if (j == 0) c += disg[node] * (acc + tg[node]);
    }
    for (int o = 32; o > 0; o >>= 1) c += __shfl_down(c, o);
    __shared__ float red[8];
    int wid = tid >> 6, lane = tid & 63;
    if (lane == 0) red[wid] = c;
    __syncthreads();
    if (tid == 0) {
        float s = 0.f;
        for (int w = 0; w < 8; ++w) s += red[w];
        fatomic(&S[g], s);
    }
}

// ---- final: score = b2 + S/N, softmax over 5 ----------------------------------
__global__ void final_kernel(const float* __restrict__ S, const float* __restrict__ b2,
                             float* __restrict__ out) {
    if (threadIdx.x == 0) {
        float sc[NGRAPH];
        float m = -1e30f;
        for (int g = 0; g < NGRAPH; ++g) {
            sc[g] = b2[0] + S[g] * (1.0f / N_);
            m = fmaxf(m, sc[g]);
        }
        float sum = 0.f;
        for (int g = 0; g < NGRAPH; ++g) { sc[g] = expf(sc[g] - m); sum += sc[g]; }
        for (int g = 0; g < NGRAPH; ++g) out[g] = sc[g] / sum;
    }
}

extern "C" void kernel_launch(void* const* d_in, const int* in_sizes, int n_in,
                              void* d_out, int out_size, void* d_ws, size_t ws_size,
                              hipStream_t stream) {
    const float* emb = (const float*)d_in[0];
    const int* ei    = (const int*)d_in[1];   // int32 (validated R2)
    const float* W1  = (const float*)d_in[2];
    const float* b1  = (const float*)d_in[3];
    const float* W2  = (const float*)d_in[4];
    const float* b2  = (const float*)d_in[5];
    float* out = (float*)d_out;

    float* S = (float*)d_ws;
    unsigned* bcurAll = (unsigned*)((char*)d_ws + 256);
    size_t hdr = 256 + (size_t)NGRAPH * NB * 4;
    hdr = (hdr + 255) & ~(size_t)255;
    char* base = (char*)d_ws + hdr;
    size_t avail = (ws_size > hdr) ? ws_size - hdr : 0;

    size_t sz_be   = (size_t)NB * CAP * 4;      // ~16.1 MB
    size_t sz_ss   = (size_t)NB * SCAP * 4;     // ~19.3 MB
    size_t sz_off  = (size_t)(NB << BSH) * 4;   // ~0.4 MB
    size_t sz_hd   = (size_t)NPAD * HID * 4;    // ~6.4 MB
    size_t sz_dis  = (size_t)N_ * 4;
    size_t sz_t    = (size_t)NPAD * 4;
    size_t per = sz_be + sz_ss + 2 * sz_off + sz_hd + sz_dis + sz_t + 1024;  // ~43.4 MB
    int maxChunk = (int)(avail / per);
    if (maxChunk > NGRAPH) maxChunk = NGRAPH;
    if (maxChunk < 1) maxChunk = 1;

    hipMemsetAsync(d_ws, 0, 256 + (size_t)NGRAPH * NB * 4, stream);

    for (int g0 = 0; g0 < NGRAPH; g0 += maxChunk) {
        int ng = (NGRAPH - g0 < maxChunk) ? (NGRAPH - g0) : maxChunk;
        char* p = base;
        unsigned* bedge = (unsigned*)p; p += (size_t)ng * sz_be;
        unsigned* ssrc  = (unsigned*)p; p += (size_t)ng * sz_ss;
        unsigned* offA  = (unsigned*)p; p += (size_t)ng * sz_off;
        unsigned* degA  = (unsigned*)p; p += (size_t)ng * sz_off;
        float* hd  = (float*)p; p += (size_t)ng * sz_hd;
        float* dis = (float*)p; p += (size_t)ng * sz_dis;
        float* t_  = (float*)p;
        unsigned* bcur = bcurAll + (size_t)g0 * NB;

        const int* eic  = ei  + (size_t)g0 * 2 * E_;
        const float* xc = emb + (size_t)g0 * N_ * DIM;

        bucket_kernel<<<dim3(128, ng), 256, 0, stream>>>(eic, bcur, bedge);
        sortb_kernel<<<dim3(NB, ng), 256, 0, stream>>>(bcur, bedge, ssrc, offA, degA, dis);
        gemm_kernel<<<dim3((ng * N_ + 255) / 256), 256, 0, stream>>>(xc, W1, dis, hd, ng);
        bagg_kernel<<<dim3(NB, ng), 512, 0, stream>>>(ssrc, offA, degA, hd, dis, b1, W2, t_);
        score2_kernel<<<dim3(NB, ng), 512, 0, stream>>>(ssrc, offA, degA, t_, dis, S + g0);
    }
    final_kernel<<<1, 64, 0, stream>>>(S, b2, out);
}

// Round 13
// 885.691 us; speedup vs baseline: 1.3050x; 1.3050x over previous
//
#include <hip/hip_runtime.h>
#include <hip/hip_bf16.h>

#define N_ 100000
#define E_ 3200000
#define DIM 300
#define HID 16
#define NGRAPH 5
#define NB 196         // buckets/graph, 512 nodes each (196*512 >= 100000)
#define BSH 9
#define BNODES 512
#define CAP 20480      // mean 16384 edges/bucket, sigma~128 -> +32 sigma
#define SCAP 24576     // CAP + 512*8 padding headroom (24064 worst case)
#define NPAD (N_ + 8)  // hd/t stride: slot N_ is the zero "dummy" node

__device__ __forceinline__ void fatomic(float* p, float v) { unsafeAtomicAdd(p, v); }

// ---- phase 1: LDS-staged radix bucketing (register-staged, CHUNK 4096) --------
__global__ __launch_bounds__(256) void bucket_kernel(const int* __restrict__ ei,
                                                     unsigned* __restrict__ bcur,
                                                     unsigned* __restrict__ bedge) {
    int g = blockIdx.y;
    const int4* src4 = (const int4*)(ei + (size_t)g * 2 * E_);
    const int4* dst4 = (const int4*)(ei + (size_t)g * 2 * E_ + E_);
    unsigned* bc = bcur + (size_t)g * NB;
    unsigned* be = bedge + (size_t)g * NB * CAP;
    __shared__ unsigned hist[NB], curs[NB];
    int tid = threadIdx.x;
    const int CHUNK = 4096;
    const int nchunk = (E_ + CHUNK - 1) / CHUNK;
    for (int c = blockIdx.x; c < nchunk; c += gridDim.x) {
        int cb = c * CHUNK;
        for (int i = tid; i < NB; i += 256) hist[i] = 0u;
        __syncthreads();
        int4 sv[4], dv[4]; bool val[4];
#pragma unroll
        for (int k = 0; k < 4; ++k) {
            int e0 = cb + k * 1024 + tid * 4;
            val[k] = (e0 < E_);
            if (val[k]) { sv[k] = src4[e0 >> 2]; dv[k] = dst4[e0 >> 2]; }
        }
#pragma unroll
        for (int k = 0; k < 4; ++k) if (val[k]) {
            atomicAdd(&hist[((unsigned)dv[k].x) >> BSH], 1u);
            atomicAdd(&hist[((unsigned)dv[k].y) >> BSH], 1u);
            atomicAdd(&hist[((unsigned)dv[k].z) >> BSH], 1u);
            atomicAdd(&hist[((unsigned)dv[k].w) >> BSH], 1u);
        }
        __syncthreads();
        for (int i = tid; i < NB; i += 256) curs[i] = atomicAdd(&bc[i], hist[i]);
        __syncthreads();
#define EMIT(S, D) { unsigned bb = ((unsigned)(D)) >> BSH; \
        unsigned pos = atomicAdd(&curs[bb], 1u); \
        if (pos < CAP) be[(size_t)bb * CAP + pos] = (((unsigned)(S)) << BSH) | (((unsigned)(D)) & (BNODES - 1)); }
#pragma unroll
        for (int k = 0; k < 4; ++k) if (val[k]) {
            EMIT(sv[k].x, dv[k].x)
            EMIT(sv[k].y, dv[k].y)
            EMIT(sv[k].z, dv[k].z)
            EMIT(sv[k].w, dv[k].w)
        }
#undef EMIT
        __syncthreads();
    }
}

// ---- phase 1.5: per-bucket counting sort + pad-fill (dummy node N_) -----------
__global__ __launch_bounds__(256) void sortb_kernel(const unsigned* __restrict__ bcur,
                                                    const unsigned* __restrict__ bedge,
                                                    unsigned* __restrict__ ssrc,
                                                    unsigned* __restrict__ offA,
                                                    unsigned* __restrict__ degA,
                                                    float* __restrict__ dis) {
    int g = blockIdx.y, b = blockIdx.x;
    __shared__ unsigned hist[BNODES], offL[BNODES], curL[BNODES], part[256];
    int tid = threadIdx.x;
    hist[tid] = 0u; hist[tid + 256] = 0u;
    __syncthreads();
    unsigned n = bcur[(size_t)g * NB + b]; if (n > CAP) n = CAP;
    const unsigned* beb = bedge + ((size_t)g * NB + b) * CAP;
    for (unsigned i = tid; i < n; i += 256) atomicAdd(&hist[beb[i] & (BNODES - 1)], 1u);
    __syncthreads();
    unsigned d0 = hist[2 * tid], d1 = hist[2 * tid + 1];
    unsigned p0 = (d0 + 7u) & ~7u, p1 = (d1 + 7u) & ~7u;
    part[tid] = p0 + p1;
    __syncthreads();
    for (int o = 1; o < 256; o <<= 1) {
        unsigned v = (tid >= o) ? part[tid - o] : 0u;
        __syncthreads();
        part[tid] += v;
        __syncthreads();
    }
    unsigned base = part[tid] - p0 - p1;   // exclusive, multiple of 8
    offL[2 * tid] = base;         curL[2 * tid] = base;
    offL[2 * tid + 1] = base + p0; curL[2 * tid + 1] = base + p0;
    int node0 = b << BSH;
    unsigned sbase = (unsigned)(((size_t)g * NB + b) * SCAP);
    float* disg = dis + (size_t)g * N_;
    unsigned* offg = offA + (size_t)g * (NB << BSH);
    unsigned* degg = degA + (size_t)g * (NB << BSH);
    {
        int i = 2 * tid, node = node0 + i;
        offg[node] = sbase + offL[i]; degg[node] = d0;
        if (node < N_) disg[node] = rsqrtf((float)d0 + 1.0f);
        for (unsigned k = d0; k < p0; ++k) ssrc[(size_t)sbase + offL[i] + k] = (unsigned)N_;
        i = 2 * tid + 1; node = node0 + i;
        offg[node] = sbase + offL[i]; degg[node] = d1;
        if (node < N_) disg[node] = rsqrtf((float)d1 + 1.0f);
        for (unsigned k = d1; k < p1; ++k) ssrc[(size_t)sbase + offL[i] + k] = (unsigned)N_;
    }
    __syncthreads();
    for (unsigned i = tid; i < n; i += 256) {
        unsigned pk = beb[i];
        unsigned pos = atomicAdd(&curL[pk & (BNODES - 1)], 1u);
        ssrc[(size_t)sbase + pos] = pk >> BSH;
    }
}

// ---- hd = (x @ W1) * dis[node]  (thread-per-node, W1 in LDS; R9-proven) -------
#define FMA4(acc, sv, wv) \
    acc.x += (sv) * (wv).x; acc.y += (sv) * (wv).y; acc.z += (sv) * (wv).z; acc.w += (sv) * (wv).w;

__global__ __launch_bounds__(256) void gemm_kernel(const float* __restrict__ x,
                                                   const float* __restrict__ W1,
                                                   const float* __restrict__ dis,
                                                   float* __restrict__ hd, int ngr) {
    __shared__ float wsh[DIM * HID];
    for (int i = threadIdx.x; i < DIM * HID; i += blockDim.x) wsh[i] = W1[i];
    // zero the per-graph dummy node line (hd[g][N_][0..15] = 0)
    if (blockIdx.x == 0 && threadIdx.x < ngr) {
        float4* pz = (float4*)(hd + ((size_t)threadIdx.x * NPAD + N_) * HID);
        float4 z = {0.f, 0.f, 0.f, 0.f};
        pz[0] = z; pz[1] = z; pz[2] = z; pz[3] = z;
    }
    __syncthreads();
    int ntot = ngr * N_;
    int node = blockIdx.x * blockDim.x + threadIdx.x;
    if (node >= ntot) return;
    const float4* xr = (const float4*)(x + (size_t)node * DIM);
    float4 a0 = {0,0,0,0}, a1 = {0,0,0,0}, a2 = {0,0,0,0}, a3 = {0,0,0,0};
    float4 q0, q1, q2, q3;
#define STEP(XS, B) \
    q0 = wr[(B)+0]; q1 = wr[(B)+1]; q2 = wr[(B)+2]; q3 = wr[(B)+3]; \
    FMA4(a0, XS, q0) FMA4(a1, XS, q1) FMA4(a2, XS, q2) FMA4(a3, XS, q3)
#pragma unroll 3
    for (int k4 = 0; k4 < DIM / 4; ++k4) {
        float4 xv = xr[k4];
        const float4* wr = (const float4*)(wsh + k4 * 4 * HID);
        STEP(xv.x, 0)
        STEP(xv.y, 4)
        STEP(xv.z, 8)
        STEP(xv.w, 12)
    }
#undef STEP
    float dn = dis[node];
    a0.x *= dn; a0.y *= dn; a0.z *= dn; a0.w *= dn;
    a1.x *= dn; a1.y *= dn; a1.z *= dn; a1.w *= dn;
    a2.x *= dn; a2.y *= dn; a2.z *= dn; a2.w *= dn;
    a3.x *= dn; a3.y *= dn; a3.z *= dn; a3.w *= dn;
    int gi = node / N_, local = node - gi * N_;
    float4* hr = (float4*)(hd + ((size_t)gi * NPAD + local) * HID);
    hr[0] = a0; hr[1] = a1; hr[2] = a2; hr[3] = a3;
}

// ---- phase 2: per-node register aggregation, padded lists, 16-deep pipeline ---
__global__ __launch_bounds__(512) void bagg_kernel(const unsigned* __restrict__ ssrc,
                                                   const unsigned* __restrict__ offA,
                                                   const unsigned* __restrict__ degA,
                                                   const float* __restrict__ hd,
                                                   const float* __restrict__ dis,
                                                   const float* __restrict__ b1,
                                                   const float* __restrict__ W2,
                                                   float* __restrict__ t_) {
    int g = blockIdx.y, b = blockIdx.x;
    const float* hdg = hd + (size_t)g * NPAD * HID;
    const float* disg = dis + (size_t)g * N_;
    const unsigned* offg = offA + (size_t)g * (NB << BSH);
    const unsigned* degg = degA + (size_t)g * (NB << BSH);
    float* tg = t_ + (size_t)g * NPAD;
    int tid = threadIdx.x, j = tid & 15, sub = tid >> 4;   // 32 node-groups
    if (b == 0 && tid == 0) tg[N_] = 0.f;                  // dummy for score2
    float b1j = b1[j], w2j = W2[j];
    int node0 = b << BSH;
#pragma unroll 1
    for (int m = 0; m < 16; ++m) {
        int node = node0 + sub + (m << 5);
        if (node >= N_) continue;
        unsigned k0 = offg[node], dg = degg[node];
        unsigned dgp = (dg + 7u) & ~7u;                    // padded: multiple of 8
        float acc = hdg[(size_t)node * HID + j];           // self-loop term
        unsigned k = 0;
        for (; k + 16 <= dgp; k += 16) {                   // 16-deep gather pipeline
            const int4* ip = (const int4*)(ssrc + k0 + k);
            int4 i0 = ip[0], i1 = ip[1], i2 = ip[2], i3 = ip[3];
            float v0 = hdg[(size_t)(unsigned)i0.x * HID + j];
            float v1 = hdg[(size_t)(unsigned)i0.y * HID + j];
            float v2 = hdg[(size_t)(unsigned)i0.z * HID + j];
            float v3 = hdg[(size_t)(unsigned)i0.w * HID + j];
            float v4 = hdg[(size_t)(unsigned)i1.x * HID + j];
            float v5 = hdg[(size_t)(unsigned)i1.y * HID + j];
            float v6 = hdg[(size_t)(unsigned)i1.z * HID + j];
            float v7 = hdg[(size_t)(unsigned)i1.w * HID + j];
            float v8 = hdg[(size_t)(unsigned)i2.x * HID + j];
            float v9 = hdg[(size_t)(unsigned)i2.y * HID + j];
            float va = hdg[(size_t)(unsigned)i2.z * HID + j];
            float vb = hdg[(size_t)(unsigned)i2.w * HID + j];
            float vc = hdg[(size_t)(unsigned)i3.x * HID + j];
            float vd = hdg[(size_t)(unsigned)i3.y * HID + j];
            float ve = hdg[(size_t)(unsigned)i3.z * HID + j];
            float vf = hdg[(size_t)(unsigned)i3.w * HID + j];
            acc += (((v0 + v1) + (v2 + v3)) + ((v4 + v5) + (v6 + v7)))
                 + (((v8 + v9) + (va + vb)) + ((vc + vd) + (ve + vf)));
        }
        for (; k < dgp; k += 8) {
            const int4* ip = (const int4*)(ssrc + k0 + k);
            int4 i0 = ip[0], i1 = ip[1];
            float v0 = hdg[(size_t)(unsigned)i0.x * HID + j];
            float v1 = hdg[(size_t)(unsigned)i0.y * HID + j];
            float v2 = hdg[(size_t)(unsigned)i0.z * HID + j];
            float v3 = hdg[(size_t)(unsigned)i0.w * HID + j];
            float v4 = hdg[(size_t)(unsigned)i1.x * HID + j];
            float v5 = hdg[(size_t)(unsigned)i1.y * HID + j];
            float v6 = hdg[(size_t)(unsigned)i1.z * HID + j];
            float v7 = hdg[(size_t)(unsigned)i1.w * HID + j];
            acc += ((v0 + v1) + (v2 + v3)) + ((v4 + v5) + (v6 + v7));
        }
        float dn = disg[node];
        float val = fmaxf(acc * dn + b1j, 0.f) * w2j;
        val += __shfl_xor(val, 1);
        val += __shfl_xor(val, 2);
        val += __shfl_xor(val, 4);
        val += __shfl_xor(val, 8);
        if (j == 0) tg[node] = val * dn;
    }
}

// ---- layer-2 via sorted padded lists ------------------------------------------
__global__ __launch_bounds__(512) void score2_kernel(const unsigned* __restrict__ ssrc,
                                                     const unsigned* __restrict__ offA,
                                                     const unsigned* __restrict__ degA,
                                                     const float* __restrict__ t_,
                                                     const float* __restrict__ dis,
                                                     float* __restrict__ S) {
    int g = blockIdx.y, b = blockIdx.x;
    const float* tg = t_ + (size_t)g * NPAD;
    const float* disg = dis + (size_t)g * N_;
    const unsigned* offg = offA + (size_t)g * (NB << BSH);
    const unsigned* degg = degA + (size_t)g * (NB << BSH);
    int tid = threadIdx.x, j = tid & 3, grp = tid >> 2;   // 128 node-groups
    int node0 = b << BSH;
    float c = 0.f;
#pragma unroll 1
    for (int m = 0; m < 4; ++m) {
        int node = node0 + grp + (m << 7);
        if (node >= N_) continue;
        unsigned k0 = offg[node], dg = degg[node];
        unsigned dgp = (dg + 7u) & ~7u;                   // t[N_] == 0: pads add 0
        float acc = 0.f;
        for (unsigned k = j; k < dgp; k += 4) acc += tg[ssrc[k0 + k]];
        acc += __shfl_xor(acc, 1);
        acc += __shfl_xor(acc, 2);
        if (j == 0) c += disg[node] * (acc + tg[node]);
    }
    for (int o = 32; o > 0; o >>= 1) c += __shfl_down(c, o);
    __shared__ float red[8];
    int wid = tid >> 6, lane = tid & 63;
    if (lane == 0) red[wid] = c;
    __syncthreads();
    if (tid == 0) {
        float s = 0.f;
        for (int w = 0; w < 8; ++w) s += red[w];
        fatomic(&S[g], s);
    }
}

// ---- final: score = b2 + S/N, softmax over 5 ----------------------------------
__global__ void final_kernel(const float* __restrict__ S, const float* __restrict__ b2,
                             float* __restrict__ out) {
    if (threadIdx.x == 0) {
        float sc[NGRAPH];
        float m = -1e30f;
        for (int g = 0; g < NGRAPH; ++g) {
            sc[g] = b2[0] + S[g] * (1.0f / N_);
            m = fmaxf(m, sc[g]);
        }
        float sum = 0.f;
        for (int g = 0; g < NGRAPH; ++g) { sc[g] = expf(sc[g] - m); sum += sc[g]; }
        for (int g = 0; g < NGRAPH; ++g) out[g] = sc[g] / sum;
    }
}

extern "C" void kernel_launch(void* const* d_in, const int* in_sizes, int n_in,
                              void* d_out, int out_size, void* d_ws, size_t ws_size,
                              hipStream_t stream) {
    const float* emb = (const float*)d_in[0];
    const int* ei    = (const int*)d_in[1];   // int32 (validated R2)
    const float* W1  = (const float*)d_in[2];
    const float* b1  = (const float*)d_in[3];
    const float* W2  = (const float*)d_in[4];
    const float* b2  = (const float*)d_in[5];
    float* out = (float*)d_out;

    float* S = (float*)d_ws;
    unsigned* bcurAll = (unsigned*)((char*)d_ws + 256);
    size_t hdr = 256 + (size_t)NGRAPH * NB * 4;
    hdr = (hdr + 255) & ~(size_t)255;
    char* base = (char*)d_ws + hdr;
    size_t avail = (ws_size > hdr) ? ws_size - hdr : 0;

    size_t sz_be   = (size_t)NB * CAP * 4;      // ~16.1 MB
    size_t sz_ss   = (size_t)NB * SCAP * 4;     // ~19.3 MB
    size_t sz_off  = (size_t)(NB << BSH) * 4;   // ~0.4 MB
    size_t sz_hd   = (size_t)NPAD * HID * 4;    // ~6.4 MB
    size_t sz_dis  = (size_t)N_ * 4;
    size_t sz_t    = (size_t)NPAD * 4;
    size_t per = sz_be + sz_ss + 2 * sz_off + sz_hd + sz_dis + sz_t + 1024;  // ~43.4 MB
    int maxChunk = (int)(avail / per);
    if (maxChunk > NGRAPH) maxChunk = NGRAPH;
    if (maxChunk < 1) maxChunk = 1;

    hipMemsetAsync(d_ws, 0, 256 + (size_t)NGRAPH * NB * 4, stream);

    for (int g0 = 0; g0 < NGRAPH; g0 += maxChunk) {
        int ng = (NGRAPH - g0 < maxChunk) ? (NGRAPH - g0) : maxChunk;
        char* p = base;
        unsigned* bedge = (unsigned*)p; p += (size_t)ng * sz_be;
        unsigned* ssrc  = (unsigned*)p; p += (size_t)ng * sz_ss;
        unsigned* offA  = (unsigned*)p; p += (size_t)ng * sz_off;
        unsigned* degA  = (unsigned*)p; p += (size_t)ng * sz_off;
        float* hd  = (float*)p; p += (size_t)ng * sz_hd;
        float* dis = (float*)p; p += (size_t)ng * sz_dis;
        float* t_  = (float*)p;
        unsigned* bcur = bcurAll + (size_t)g0 * NB;

        const int* eic  = ei  + (size_t)g0 * 2 * E_;
        const float* xc = emb + (size_t)g0 * N_ * DIM;

        bucket_kernel<<<dim3(128, ng), 256, 0, stream>>>(eic, bcur, bedge);
        sortb_kernel<<<dim3(NB, ng), 256, 0, stream>>>(bcur, bedge, ssrc, offA, degA, dis);
        gemm_kernel<<<dim3((ng * N_ + 255) / 256), 256, 0, stream>>>(xc, W1, dis, hd, ng);
        bagg_kernel<<<dim3(NB, ng), 512, 0, stream>>>(ssrc, offA, degA, hd, dis, b1, W2, t_);
        score2_kernel<<<dim3(NB, ng), 512, 0, stream>>>(ssrc, offA, degA, t_, dis, S + g0);
    }
    final_kernel<<<1, 64, 0, stream>>>(S, b2, out);
}

// Round 14
// 881.351 us; speedup vs baseline: 1.3114x; 1.0049x over previous
//
#include <hip/hip_runtime.h>
#include <hip/hip_bf16.h>

#define N_ 100000
#define E_ 3200000
#define DIM 300
#define HID 16
#define NGRAPH 5
#define NB 196         // buckets/graph, 512 nodes each (196*512 >= 100000)
#define BSH 9
#define BNODES 512
#define CAP 20480      // mean 16384 edges/bucket, sigma~128 -> +32 sigma
#define SCAP 24576     // CAP + 512*8 padding headroom (24064 worst case)
#define NPAD (N_ + 8)  // hd/t stride: slot N_ is the zero "dummy" node

__device__ __forceinline__ void fatomic(float* p, float v) { unsafeAtomicAdd(p, v); }

// ---- phase 1: LDS-staged radix bucketing (register-staged, CHUNK 4096) --------
__global__ __launch_bounds__(256) void bucket_kernel(const int* __restrict__ ei,
                                                     unsigned* __restrict__ bcur,
                                                     unsigned* __restrict__ bedge) {
    int g = blockIdx.y;
    const int4* src4 = (const int4*)(ei + (size_t)g * 2 * E_);
    const int4* dst4 = (const int4*)(ei + (size_t)g * 2 * E_ + E_);
    unsigned* bc = bcur + (size_t)g * NB;
    unsigned* be = bedge + (size_t)g * NB * CAP;
    __shared__ unsigned hist[NB], curs[NB];
    int tid = threadIdx.x;
    const int CHUNK = 4096;
    const int nchunk = (E_ + CHUNK - 1) / CHUNK;
    for (int c = blockIdx.x; c < nchunk; c += gridDim.x) {
        int cb = c * CHUNK;
        for (int i = tid; i < NB; i += 256) hist[i] = 0u;
        __syncthreads();
        int4 sv[4], dv[4]; bool val[4];
#pragma unroll
        for (int k = 0; k < 4; ++k) {
            int e0 = cb + k * 1024 + tid * 4;
            val[k] = (e0 < E_);
            if (val[k]) { sv[k] = src4[e0 >> 2]; dv[k] = dst4[e0 >> 2]; }
        }
#pragma unroll
        for (int k = 0; k < 4; ++k) if (val[k]) {
            atomicAdd(&hist[((unsigned)dv[k].x) >> BSH], 1u);
            atomicAdd(&hist[((unsigned)dv[k].y) >> BSH], 1u);
            atomicAdd(&hist[((unsigned)dv[k].z) >> BSH], 1u);
            atomicAdd(&hist[((unsigned)dv[k].w) >> BSH], 1u);
        }
        __syncthreads();
        for (int i = tid; i < NB; i += 256) curs[i] = atomicAdd(&bc[i], hist[i]);
        __syncthreads();
#define EMIT(S, D) { unsigned bb = ((unsigned)(D)) >> BSH; \
        unsigned pos = atomicAdd(&curs[bb], 1u); \
        if (pos < CAP) be[(size_t)bb * CAP + pos] = (((unsigned)(S)) << BSH) | (((unsigned)(D)) & (BNODES - 1)); }
#pragma unroll
        for (int k = 0; k < 4; ++k) if (val[k]) {
            EMIT(sv[k].x, dv[k].x)
            EMIT(sv[k].y, dv[k].y)
            EMIT(sv[k].z, dv[k].z)
            EMIT(sv[k].w, dv[k].w)
        }
#undef EMIT
        __syncthreads();
    }
}

// ---- phase 1.5: per-bucket counting sort + pad-fill (dummy node N_) -----------
__global__ __launch_bounds__(256) void sortb_kernel(const unsigned* __restrict__ bcur,
                                                    const unsigned* __restrict__ bedge,
                                                    unsigned* __restrict__ ssrc,
                                                    unsigned* __restrict__ offA,
                                                    unsigned* __restrict__ degA,
                                                    float* __restrict__ dis) {
    int g = blockIdx.y, b = blockIdx.x;
    __shared__ unsigned hist[BNODES], offL[BNODES], curL[BNODES], part[256];
    int tid = threadIdx.x;
    hist[tid] = 0u; hist[tid + 256] = 0u;
    __syncthreads();
    unsigned n = bcur[(size_t)g * NB + b]; if (n > CAP) n = CAP;
    const unsigned* beb = bedge + ((size_t)g * NB + b) * CAP;
    for (unsigned i = tid; i < n; i += 256) atomicAdd(&hist[beb[i] & (BNODES - 1)], 1u);
    __syncthreads();
    unsigned d0 = hist[2 * tid], d1 = hist[2 * tid + 1];
    unsigned p0 = (d0 + 7u) & ~7u, p1 = (d1 + 7u) & ~7u;
    part[tid] = p0 + p1;
    __syncthreads();
    for (int o = 1; o < 256; o <<= 1) {
        unsigned v = (tid >= o) ? part[tid - o] : 0u;
        __syncthreads();
        part[tid] += v;
        __syncthreads();
    }
    unsigned base = part[tid] - p0 - p1;   // exclusive, multiple of 8
    offL[2 * tid] = base;         curL[2 * tid] = base;
    offL[2 * tid + 1] = base + p0; curL[2 * tid + 1] = base + p0;
    int node0 = b << BSH;
    unsigned sbase = (unsigned)(((size_t)g * NB + b) * SCAP);
    float* disg = dis + (size_t)g * N_;
    unsigned* offg = offA + (size_t)g * (NB << BSH);
    unsigned* degg = degA + (size_t)g * (NB << BSH);
    {
        int i = 2 * tid, node = node0 + i;
        offg[node] = sbase + offL[i]; degg[node] = d0;
        if (node < N_) disg[node] = rsqrtf((float)d0 + 1.0f);
        for (unsigned k = d0; k < p0; ++k) ssrc[(size_t)sbase + offL[i] + k] = (unsigned)N_;
        i = 2 * tid + 1; node = node0 + i;
        offg[node] = sbase + offL[i]; degg[node] = d1;
        if (node < N_) disg[node] = rsqrtf((float)d1 + 1.0f);
        for (unsigned k = d1; k < p1; ++k) ssrc[(size_t)sbase + offL[i] + k] = (unsigned)N_;
    }
    __syncthreads();
    for (unsigned i = tid; i < n; i += 256) {
        unsigned pk = beb[i];
        unsigned pos = atomicAdd(&curL[pk & (BNODES - 1)], 1u);
        ssrc[(size_t)sbase + pos] = pk >> BSH;
    }
}

// ---- hd = (x @ W1) * dis[node] -- thread-per-node, W1 read DIRECT from global -
// All lanes read the same W1 address (k uniform) -> scalar/constant-cache path.
// No LDS, no barriers; removes the 1200 ds_read_b128/node that limited R13 gemm.
#define FMA4(acc, sv, wv) \
    acc.x += (sv) * (wv).x; acc.y += (sv) * (wv).y; acc.z += (sv) * (wv).z; acc.w += (sv) * (wv).w;

__global__ __launch_bounds__(256) void gemm_kernel(const float* __restrict__ x,
                                                   const float* __restrict__ W1,
                                                   const float* __restrict__ dis,
                                                   float* __restrict__ hd, int ngr) {
    // zero the per-graph dummy node line (hd[g][N_][0..15] = 0)
    if (blockIdx.x == 0 && threadIdx.x < ngr) {
        float4* pz = (float4*)(hd + ((size_t)threadIdx.x * NPAD + N_) * HID);
        float4 z = {0.f, 0.f, 0.f, 0.f};
        pz[0] = z; pz[1] = z; pz[2] = z; pz[3] = z;
    }
    int ntot = ngr * N_;
    int node = blockIdx.x * blockDim.x + threadIdx.x;
    if (node >= ntot) return;
    const float4* xr = (const float4*)(x + (size_t)node * DIM);
    const float4* wbase = (const float4*)W1;
    float4 a0 = {0,0,0,0}, a1 = {0,0,0,0}, a2 = {0,0,0,0}, a3 = {0,0,0,0};
    float4 q0, q1, q2, q3;
#define STEP(XS, B) \
    q0 = wrk[(B)+0]; q1 = wrk[(B)+1]; q2 = wrk[(B)+2]; q3 = wrk[(B)+3]; \
    FMA4(a0, XS, q0) FMA4(a1, XS, q1) FMA4(a2, XS, q2) FMA4(a3, XS, q3)
#pragma unroll 3
    for (int k4 = 0; k4 < DIM / 4; ++k4) {
        float4 xv = xr[k4];
        const float4* wrk = wbase + k4 * 16;   // wave-uniform address
        STEP(xv.x, 0)
        STEP(xv.y, 4)
        STEP(xv.z, 8)
        STEP(xv.w, 12)
    }
#undef STEP
    float dn = dis[node];
    a0.x *= dn; a0.y *= dn; a0.z *= dn; a0.w *= dn;
    a1.x *= dn; a1.y *= dn; a1.z *= dn; a1.w *= dn;
    a2.x *= dn; a2.y *= dn; a2.z *= dn; a2.w *= dn;
    a3.x *= dn; a3.y *= dn; a3.z *= dn; a3.w *= dn;
    int gi = node / N_, local = node - gi * N_;
    float4* hr = (float4*)(hd + ((size_t)gi * NPAD + local) * HID);
    hr[0] = a0; hr[1] = a1; hr[2] = a2; hr[3] = a3;
}

// ---- phase 2: per-node register aggregation, padded lists, 16-deep pipeline ---
__global__ __launch_bounds__(512) void bagg_kernel(const unsigned* __restrict__ ssrc,
                                                   const unsigned* __restrict__ offA,
                                                   const unsigned* __restrict__ degA,
                                                   const float* __restrict__ hd,
                                                   const float* __restrict__ dis,
                                                   const float* __restrict__ b1,
                                                   const float* __restrict__ W2,
                                                   float* __restrict__ t_) {
    int g = blockIdx.y, b = blockIdx.x;
    const float* hdg = hd + (size_t)g * NPAD * HID;
    const float* disg = dis + (size_t)g * N_;
    const unsigned* offg = offA + (size_t)g * (NB << BSH);
    const unsigned* degg = degA + (size_t)g * (NB << BSH);
    float* tg = t_ + (size_t)g * NPAD;
    int tid = threadIdx.x, j = tid & 15, sub = tid >> 4;   // 32 node-groups
    if (b == 0 && tid == 0) tg[N_] = 0.f;                  // dummy for score2
    float b1j = b1[j], w2j = W2[j];
    int node0 = b << BSH;
#pragma unroll 1
    for (int m = 0; m < 16; ++m) {
        int node = node0 + sub + (m << 5);
        if (node >= N_) continue;
        unsigned k0 = offg[node], dg = degg[node];
        unsigned dgp = (dg + 7u) & ~7u;                    // padded: multiple of 8
        float acc = hdg[(size_t)node * HID + j];           // self-loop term
        unsigned k = 0;
        for (; k + 16 <= dgp; k += 16) {                   // 16-deep gather pipeline
            const int4* ip = (const int4*)(ssrc + k0 + k);
            int4 i0 = ip[0], i1 = ip[1], i2 = ip[2], i3 = ip[3];
            float v0 = hdg[(size_t)(unsigned)i0.x * HID + j];
            float v1 = hdg[(size_t)(unsigned)i0.y * HID + j];
            float v2 = hdg[(size_t)(unsigned)i0.z * HID + j];
            float v3 = hdg[(size_t)(unsigned)i0.w * HID + j];
            float v4 = hdg[(size_t)(unsigned)i1.x * HID + j];
            float v5 = hdg[(size_t)(unsigned)i1.y * HID + j];
            float v6 = hdg[(size_t)(unsigned)i1.z * HID + j];
            float v7 = hdg[(size_t)(unsigned)i1.w * HID + j];
            float v8 = hdg[(size_t)(unsigned)i2.x * HID + j];
            float v9 = hdg[(size_t)(unsigned)i2.y * HID + j];
            float va = hdg[(size_t)(unsigned)i2.z * HID + j];
            float vb = hdg[(size_t)(unsigned)i2.w * HID + j];
            float vc = hdg[(size_t)(unsigned)i3.x * HID + j];
            float vd = hdg[(size_t)(unsigned)i3.y * HID + j];
            float ve = hdg[(size_t)(unsigned)i3.z * HID + j];
            float vf = hdg[(size_t)(unsigned)i3.w * HID + j];
            acc += (((v0 + v1) + (v2 + v3)) + ((v4 + v5) + (v6 + v7)))
                 + (((v8 + v9) + (va + vb)) + ((vc + vd) + (ve + vf)));
        }
        for (; k < dgp; k += 8) {
            const int4* ip = (const int4*)(ssrc + k0 + k);
            int4 i0 = ip[0], i1 = ip[1];
            float v0 = hdg[(size_t)(unsigned)i0.x * HID + j];
            float v1 = hdg[(size_t)(unsigned)i0.y * HID + j];
            float v2 = hdg[(size_t)(unsigned)i0.z * HID + j];
            float v3 = hdg[(size_t)(unsigned)i0.w * HID + j];
            float v4 = hdg[(size_t)(unsigned)i1.x * HID + j];
            float v5 = hdg[(size_t)(unsigned)i1.y * HID + j];
            float v6 = hdg[(size_t)(unsigned)i1.z * HID + j];
            float v7 = hdg[(size_t)(unsigned)i1.w * HID + j];
            acc += ((v0 + v1) + (v2 + v3)) + ((v4 + v5) + (v6 + v7));
        }
        float dn = disg[node];
        float val = fmaxf(acc * dn + b1j, 0.f) * w2j;
        val += __shfl_xor(val, 1);
        val += __shfl_xor(val, 2);
        val += __shfl_xor(val, 4);
        val += __shfl_xor(val, 8);
        if (j == 0) tg[node] = val * dn;
    }
}

// ---- layer-2 via sorted padded lists ------------------------------------------
__global__ __launch_bounds__(512) void score2_kernel(const unsigned* __restrict__ ssrc,
                                                     const unsigned* __restrict__ offA,
                                                     const unsigned* __restrict__ degA,
                                                     const float* __restrict__ t_,
                                                     const float* __restrict__ dis,
                                                     float* __restrict__ S) {
    int g = blockIdx.y, b = blockIdx.x;
    const float* tg = t_ + (size_t)g * NPAD;
    const float* disg = dis + (size_t)g * N_;
    const unsigned* offg = offA + (size_t)g * (NB << BSH);
    const unsigned* degg = degA + (size_t)g * (NB << BSH);
    int tid = threadIdx.x, j = tid & 3, grp = tid >> 2;   // 128 node-groups
    int node0 = b << BSH;
    float c = 0.f;
#pragma unroll 1
    for (int m = 0; m < 4; ++m) {
        int node = node0 + grp + (m << 7);
        if (node >= N_) continue;
        unsigned k0 = offg[node], dg = degg[node];
        unsigned dgp = (dg + 7u) & ~7u;                   // t[N_] == 0: pads add 0
        float acc = 0.f;
        for (unsigned k = j; k < dgp; k += 4) acc += tg[ssrc[k0 + k]];
        acc += __shfl_xor(acc, 1);
        acc += __shfl_xor(acc, 2);
        if (j == 0) c += disg[node] * (acc + tg[node]);
    }
    for (int o = 32; o > 0; o >>= 1) c += __shfl_down(c, o);
    __shared__ float red[8];
    int wid = tid >> 6, lane = tid & 63;
    if (lane == 0) red[wid] = c;
    __syncthreads();
    if (tid == 0) {
        float s = 0.f;
        for (int w = 0; w < 8; ++w) s += red[w];
        fatomic(&S[g], s);
    }
}

// ---- final: score = b2 + S/N, softmax over 5 ----------------------------------
__global__ void final_kernel(const float* __restrict__ S, const float* __restrict__ b2,
                             float* __restrict__ out) {
    if (threadIdx.x == 0) {
        float sc[NGRAPH];
        float m = -1e30f;
        for (int g = 0; g < NGRAPH; ++g) {
            sc[g] = b2[0] + S[g] * (1.0f / N_);
            m = fmaxf(m, sc[g]);
        }
        float sum = 0.f;
        for (int g = 0; g < NGRAPH; ++g) { sc[g] = expf(sc[g] - m); sum += sc[g]; }
        for (int g = 0; g < NGRAPH; ++g) out[g] = sc[g] / sum;
    }
}

extern "C" void kernel_launch(void* const* d_in, const int* in_sizes, int n_in,
                              void* d_out, int out_size, void* d_ws, size_t ws_size,
                              hipStream_t stream) {
    const float* emb = (const float*)d_in[0];
    const int* ei    = (const int*)d_in[1];   // int32 (validated R2)
    const float* W1  = (const float*)d_in[2];
    const float* b1  = (const float*)d_in[3];
    const float* W2  = (const float*)d_in[4];
    const float* b2  = (const float*)d_in[5];
    float* out = (float*)d_out;

    float* S = (float*)d_ws;
    unsigned* bcurAll = (unsigned*)((char*)d_ws + 256);
    size_t hdr = 256 + (size_t)NGRAPH * NB * 4;
    hdr = (hdr + 255) & ~(size_t)255;
    char* base = (char*)d_ws + hdr;
    size_t avail = (ws_size > hdr) ? ws_size - hdr : 0;

    size_t sz_be   = (size_t)NB * CAP * 4;      // ~16.1 MB
    size_t sz_ss   = (size_t)NB * SCAP * 4;     // ~19.3 MB
    size_t sz_off  = (size_t)(NB << BSH) * 4;   // ~0.4 MB
    size_t sz_hd   = (size_t)NPAD * HID * 4;    // ~6.4 MB
    size_t sz_dis  = (size_t)N_ * 4;
    size_t sz_t    = (size_t)NPAD * 4;
    size_t per = sz_be + sz_ss + 2 * sz_off + sz_hd + sz_dis + sz_t + 1024;  // ~43.4 MB
    int maxChunk = (int)(avail / per);
    if (maxChunk > NGRAPH) maxChunk = NGRAPH;
    if (maxChunk < 1) maxChunk = 1;

    hipMemsetAsync(d_ws, 0, 256 + (size_t)NGRAPH * NB * 4, stream);

    for (int g0 = 0; g0 < NGRAPH; g0 += maxChunk) {
        int ng = (NGRAPH - g0 < maxChunk) ? (NGRAPH - g0) : maxChunk;
        char* p = base;
        unsigned* bedge = (unsigned*)p; p += (size_t)ng * sz_be;
        unsigned* ssrc  = (unsigned*)p; p += (size_t)ng * sz_ss;
        unsigned* offA  = (unsigned*)p; p += (size_t)ng * sz_off;
        unsigned* degA  = (unsigned*)p; p += (size_t)ng * sz_off;
        float* hd  = (float*)p; p += (size_t)ng * sz_hd;
        float* dis = (float*)p; p += (size_t)ng * sz_dis;
        float* t_  = (float*)p;
        unsigned* bcur = bcurAll + (size_t)g0 * NB;

        const int* eic  = ei  + (size_t)g0 * 2 * E_;
        const float* xc = emb + (size_t)g0 * N_ * DIM;

        bucket_kernel<<<dim3(128, ng), 256, 0, stream>>>(eic, bcur, bedge);
        sortb_kernel<<<dim3(NB, ng), 256, 0, stream>>>(bcur, bedge, ssrc, offA, degA, dis);
        gemm_kernel<<<dim3((ng * N_ + 255) / 256), 256, 0, stream>>>(xc, W1, dis, hd, ng);
        bagg_kernel<<<dim3(NB, ng), 512, 0, stream>>>(ssrc, offA, degA, hd, dis, b1, W2, t_);
        score2_kernel<<<dim3(NB, ng), 512, 0, stream>>>(ssrc, offA, degA, t_, dis, S + g0);
    }
    final_kernel<<<1, 64, 0, stream>>>(S, b2, out);
}